// Round 8
// baseline (115.976 us; speedup 1.0000x reference)
//
#include <hip/hip_runtime.h>
#include <hip/hip_bf16.h>

#define B_   32
#define C_   128
#define L_   4096
#define P_   100
#define NPT  7            // p-tiles of 16 (P padded to 112)
#define Q_   20
#define NBIN 21
#define NCH  (NPT * 4)    // 28 A-frag chunks; chunk = pt*4 + ks
#define CHS  512          // shorts per chunk = 64 lanes * 8 bf16 (1 KB)
#define NLB  32           // l-chunks per b (L/128)
#define HSZ  (P_ * NBIN)  // ints per block histogram (2100)
#define WS_HIST_OFF 32768 // byte offset of hist region in d_ws (Wf occupies first 28672)

typedef short          bf16x8 __attribute__((ext_vector_type(8)));
typedef float          f32x4  __attribute__((ext_vector_type(4)));
typedef unsigned short u16x8  __attribute__((ext_vector_type(8)));

// threshold tables (filled by prep_thr_kernel) -- declared BEFORE use (R7 fix)
__device__ float mn_c[P_];
__device__ float invd_c[P_];

__device__ inline unsigned short f2bf(float f) {
    __hip_bfloat16 h = __float2bfloat16(f);   // RNE
    unsigned short u; __builtin_memcpy(&u, &h, 2);
    return u;
}

// ---- prep: W (fp32 [P][C]) -> bf16 A-fragment lane order in d_ws ----
// Wf[chunk][lane][j], chunk=pt*4+ks: value = W[pt*16+(lane&15)][ks*32+(lane>>4)*8+j]
// (rows p>=100 zeroed). Main kernel reads afrag as 16B at lane*16 -> canonical
// conflict-free ds_read_b128 after a plain dwordx4 LDS copy.
__global__ void prep_w_kernel(const float* __restrict__ W, unsigned short* __restrict__ Wf) {
    const int t = blockIdx.x * 256 + threadIdx.x;     // 0 .. NCH*64-1
    if (t >= NCH * 64) return;
    const int chunk = t >> 6, lane = t & 63;
    const int pt = chunk >> 2, ks = chunk & 3;
    const int p  = pt * 16 + (lane & 15);
    const int c0 = ks * 32 + (lane >> 4) * 8;
    u16x8 v;
#pragma unroll
    for (int j = 0; j < 8; ++j)
        v[j] = (p < P_) ? f2bf(W[p * C_ + c0 + j]) : (unsigned short)0;
    *(u16x8*)(Wf + (size_t)t * 8) = v;
}

__global__ void prep_thr_kernel(const float* __restrict__ minv, const float* __restrict__ maxv) {
    const int p = threadIdx.x;
    if (p < P_) {
        const float mn = minv[p];
        mn_c[p]   = mn;
        invd_c[p] = (float)NBIN / (maxv[p] - mn);
    }
}

// ---- main: identical compute to R6; epilogue dumps the block-local histogram
// to d_ws with plain coalesced stores. NO global atomics anywhere (R6 post-mortem:
// 2M far-atomic fp32 adds onto 64k addresses, 32-way same-address contention,
// were the hidden O(20+ us) floor).
__global__ __launch_bounds__(256, 4)
void radon_mfma4_kernel(const float* __restrict__ X, const unsigned short* __restrict__ Wf,
                        int* __restrict__ hist_out) {
    __shared__ unsigned short Wlds[NCH * CHS];   // 28.0 KB
    __shared__ int hist[HSZ];                    // 8.4 KB

    const int tid  = threadIdx.x;
    const int b    = blockIdx.y;
    const int lblk = blockIdx.x;       // 0..31
    const int wave = tid >> 6;
    const int lane = tid & 63;
    const int quad = lane >> 4;
    const int nn   = lane & 15;

    // ---- Phase A: W fragments -> LDS, hist zero, the ONLY pre-epilogue barrier
    {
        const int4* src = (const int4*)Wf;
        int4* dst = (int4*)Wlds;
#pragma unroll
        for (int k = 0; k < NCH * 64 / 256; ++k)     // 7 iters, L2-resident
            dst[tid + k * 256] = src[tid + k * 256];
    }
    for (int i = tid; i < HSZ; i += 256) hist[i] = 0;
    __syncthreads();

    // ---- Phase B: X loads (once, coalesced) + packed cvt to bf16 B-frags
    const int l0 = lblk * 128 + wave * 32;
    const float* Xb = X + (size_t)b * C_ * L_;
    float xv[2][4][8];
#pragma unroll
    for (int lt = 0; lt < 2; ++lt)
#pragma unroll
        for (int ks = 0; ks < 4; ++ks)
#pragma unroll
            for (int j = 0; j < 8; ++j)
                xv[lt][ks][j] = Xb[(size_t)(ks * 32 + quad * 8 + j) * L_ + l0 + lt * 16 + nn];

    bf16x8 bfrag[2][4];
#pragma unroll
    for (int lt = 0; lt < 2; ++lt)
#pragma unroll
        for (int ks = 0; ks < 4; ++ks) {
            unsigned int u[4];
#pragma unroll
            for (int jp = 0; jp < 4; ++jp) {
                __hip_bfloat162 h2 = __float22bfloat162_rn(
                    make_float2(xv[lt][ks][2 * jp], xv[lt][ks][2 * jp + 1]));
                __builtin_memcpy(&u[jp], &h2, 4);
            }
            __builtin_memcpy(&bfrag[lt][ks], u, 16);
        }

    // ---- Phase C: 7 p-tiles, no barrier: ds_read A-frags + 8 MFMAs + bucket
    for (int pt = 0; pt < NPT; ++pt) {
        bf16x8 afrag[4];
#pragma unroll
        for (int ks = 0; ks < 4; ++ks)
            afrag[ks] = *(const bf16x8*)(&Wlds[((pt * 4 + ks) * 64 + lane) * 8]);

        f32x4 acc0 = {0.f, 0.f, 0.f, 0.f};
        f32x4 acc1 = {0.f, 0.f, 0.f, 0.f};
#pragma unroll
        for (int ks = 0; ks < 4; ++ks) {
            acc0 = __builtin_amdgcn_mfma_f32_16x16x32_bf16(afrag[ks], bfrag[0][ks], acc0, 0, 0, 0);
            acc1 = __builtin_amdgcn_mfma_f32_16x16x32_bf16(afrag[ks], bfrag[1][ks], acc1, 0, 0, 0);
        }

        // D row = quad*4 + r -> p = pt*16 + quad*4 + r (skip pad rows)
#pragma unroll
        for (int r = 0; r < 4; ++r) {
            const int p = pt * 16 + quad * 4 + r;
            if (p < P_) {
                const float mn   = mn_c[p];
                const float invd = invd_c[p];
                {
                    const float t = (acc0[r] - mn) * invd;
                    int k = 0;
                    if (t > 0.f) { const int ki = (int)t; k = (ki > 20) ? 20 : ki; }
                    atomicAdd(&hist[p * NBIN + k], 1);
                }
                {
                    const float t = (acc1[r] - mn) * invd;
                    int k = 0;
                    if (t > 0.f) { const int ki = (int)t; k = (ki > 20) ? 20 : ki; }
                    atomicAdd(&hist[p * NBIN + k], 1);
                }
            }
        }
    }
    __syncthreads();

    // ---- Phase D: dump block histogram -- plain coalesced stores, no atomics
    int* dst = hist_out + (size_t)(b * NLB + lblk) * HSZ;
    for (int i = tid; i < HSZ; i += 256) dst[i] = hist[i];
}

// ---- reducer: one workgroup per b. Sum 32 chunk-histograms, prefix-sum,
// scale, plain stores covering every output element (memset not needed).
__global__ __launch_bounds__(128)
void reduce_kernel(const int* __restrict__ hist_in, float* __restrict__ out) {
    const int b = blockIdx.x;
    const int p = threadIdx.x;
    if (p >= P_) return;
    int acc[NBIN];
#pragma unroll
    for (int k = 0; k < NBIN; ++k) acc[k] = 0;
    const int* base = hist_in + (size_t)b * NLB * HSZ + p * NBIN;
    for (int lb = 0; lb < NLB; ++lb) {
        const int* h = base + (size_t)lb * HSZ;
#pragma unroll
        for (int k = 0; k < NBIN; ++k) acc[k] += h[k];
    }
    float* o = out + ((size_t)b * P_ + p) * Q_;
    int s = 0;
#pragma unroll
    for (int qi = 0; qi < Q_; ++qi) {
        s += acc[qi];
        o[qi] = (float)s * (1.0f / (float)L_);
    }
}

extern "C" void kernel_launch(void* const* d_in, const int* in_sizes, int n_in,
                              void* d_out, int out_size, void* d_ws, size_t ws_size,
                              hipStream_t stream) {
    const float* X  = (const float*)d_in[0];
    const float* W  = (const float*)d_in[1];
    const float* mn = (const float*)d_in[2];
    const float* mx = (const float*)d_in[3];
    float* out = (float*)d_out;
    unsigned short* Wf = (unsigned short*)d_ws;                       // 28672 B
    int* hist_ws = (int*)((char*)d_ws + WS_HIST_OFF);                 // 32*32*2100*4 = 8.6 MB

    prep_w_kernel<<<NCH * 64 / 256, 256, 0, stream>>>(W, Wf);
    prep_thr_kernel<<<1, 128, 0, stream>>>(mn, mx);

    dim3 grid(NLB, B_);
    radon_mfma4_kernel<<<grid, dim3(256), 0, stream>>>(X, Wf, hist_ws);

    reduce_kernel<<<B_, 128, 0, stream>>>(hist_ws, out);
}